// Round 7
// baseline (409.756 us; speedup 1.0000x reference)
//
#include <hip/hip_runtime.h>

// Problem constants
constexpr int Bn = 32, Ln = 1855, Kn = 7, Tn = 40, CIn = 8, COn = 32, TKSn = 5, TOn = 36;
constexpr int BG   = 8;               // b per (bg) group (fallback)
constexpr int KRED = Kn * TKSn * CIn; // 280
constexpr int KPAD = 288;             // padded K (9 chunks of 32), [280,288) zero
constexpr int WROW = 296;             // fallback kernel's padded wt row
constexpr int XS_ELEMS = BG * Kn * Tn * CIn;  // fallback: 17920 bf16
constexpr int XB  = 2;                        // main: batches per block
constexpr size_t XN = (size_t)Bn * Ln * Tn * CIn; // 18,995,200 elems

// workspace layout (bytes)
constexpr size_t WS_WT   = 0;                     // 32*288 bf16 = 18432 B
constexpr size_t WS_XBF  = 18560;                 // XN bf16 = 37,990,400 B
constexpr size_t WS_ZROW = WS_XBF + XN * 2;       // 128 B zero row (invalid/pad loads)
constexpr size_t WS_NEED = WS_ZROW + 128;
constexpr unsigned ZOFF_U = (unsigned)(XN * 2);   // zero-row byte offset from xbf

typedef __attribute__((ext_vector_type(8))) short bf16x8;          // 8 bf16 = 4 VGPRs
typedef __attribute__((ext_vector_type(8))) unsigned short u16x8;
typedef __attribute__((ext_vector_type(4))) float f32x4;           // MFMA C/D

__device__ inline unsigned short f2bf(float f) {
    unsigned u = __builtin_bit_cast(unsigned, f);
    u += 0x7fffu + ((u >> 16) & 1u); // RNE
    return (unsigned short)(u >> 16);
}

// ---- combined prep kernel: blocks [0,2048) convert x, block 2048 does w ----
__global__ __launch_bounds__(256) void prep_all(const float* __restrict__ x,
                                                unsigned short* __restrict__ xbf,
                                                const float* __restrict__ w,
                                                unsigned short* __restrict__ wt,
                                                unsigned short* __restrict__ zrow) {
    const int tid = threadIdx.x;
    if (blockIdx.x == 2048) {
        for (int p = tid; p < KRED * COn; p += 256) { // 8960
            int o  = p & 31;
            int kr = p >> 5;                          // (k*5+tau)*8+i
            wt[o * KPAD + kr] = f2bf(w[p]);
        }
        for (int p = tid; p < COn * (KPAD - KRED); p += 256) { // 256
            int o = p >> 3;
            wt[o * KPAD + KRED + (p & 7)] = 0;
        }
        if (tid < 64) zrow[tid] = 0; // 128 B zeros
        return;
    }
    const size_t n8 = XN / 8; // 2,374,400 groups of 8
    for (size_t p = (size_t)blockIdx.x * 256 + tid; p < n8; p += (size_t)2048 * 256) {
        float4 a = ((const float4*)x)[2 * p];
        float4 b = ((const float4*)x)[2 * p + 1];
        u16x8 v;
        v[0] = f2bf(a.x); v[1] = f2bf(a.y); v[2] = f2bf(a.z); v[3] = f2bf(a.w);
        v[4] = f2bf(b.x); v[5] = f2bf(b.y); v[6] = f2bf(b.z); v[7] = f2bf(b.w);
        *(u16x8*)&xbf[p * 8] = v;
    }
}

// ---- NT row-tiles x 32 cols; A-fragments loaded DIRECTLY from global (L2) ----
// Address = xb + soffv[i] + voff[c]  ==  xbf[((b0+bl)*Ln + l2[k])*320 + (t+tau)*8]
// Invalid neighbor / K-pad lanes read the zero row at ZOFF_U.
// TAIL: last tile is the half-tile (rows 64..71 valid): lanes lrow>=8 duplicate
// rows 64..71 (valid addresses); their D-rows (quad>=2) masked at the store.
template<int RT0, int NT, bool TAIL>
__device__ __forceinline__ void do_tiles7(
    const char* __restrict__ xb,
    const unsigned (&voff)[9], const bool (&vld)[9],
    const bf16x8 (&bfrag)[2][9], float bv0, float bv1,
    float* __restrict__ out, int b0, int l, int quad, int lrow)
{
    f32x4 acc[NT][2];
    unsigned soffv[NT];
    #pragma unroll
    for (int i = 0; i < NT; ++i) {
        acc[i][0] = f32x4{0.f,0.f,0.f,0.f};
        acc[i][1] = f32x4{0.f,0.f,0.f,0.f};
        int m;
        if (TAIL && i == NT - 1) m = 64 + (lrow & 7);   // remap invalid rows
        else                     m = (RT0 + i) * 16 + lrow;
        const int bl = m / 36, t = m - bl * 36;         // per-lane; folded into soffv
        soffv[i] = (unsigned)((b0 + bl) * Ln) * 640u + (unsigned)t * 16u;
    }
    __builtin_amdgcn_s_setprio(1);
    #pragma unroll
    for (int c = 0; c < 9; ++c) {
        #pragma unroll
        for (int i = 0; i < NT; ++i) {
            const unsigned vo = vld[c] ? (soffv[i] + voff[c]) : ZOFF_U;
            bf16x8 a = *(const bf16x8*)(xb + vo);
            acc[i][0] = __builtin_amdgcn_mfma_f32_16x16x32_bf16(a, bfrag[0][c], acc[i][0], 0, 0, 0);
            acc[i][1] = __builtin_amdgcn_mfma_f32_16x16x32_bf16(a, bfrag[1][c], acc[i][1], 0, 0, 0);
        }
    }
    __builtin_amdgcn_s_setprio(0);
    // epilogue: C/D layout col=lane&15, row=quad*4+reg  [m89/m91 verified]
    #pragma unroll
    for (int i = 0; i < NT; ++i) {
        const bool tail_tile = TAIL && (i == NT - 1);
        if (tail_tile && quad >= 2) continue;  // masked garbage rows (72..79)
        #pragma unroll
        for (int reg = 0; reg < 4; ++reg) {
            const int m  = (RT0 + i) * 16 + quad * 4 + reg;
            const int bl = m / 36, t = m - bl * 36;
            const size_t off =
                (((size_t)(b0 + bl) * Ln + l) * TOn + t) * COn + lrow;
            __builtin_nontemporal_store(acc[i][0][reg] + bv0, &out[off]);
            __builtin_nontemporal_store(acc[i][1][reg] + bv1, &out[off + 16]);
        }
    }
}

// ---- main kernel: 1 wave/block, 72 rows x 32 cols, NO LDS, no barriers ----
__global__ __launch_bounds__(64, 3) void conv_mfma7(
    const unsigned short* __restrict__ xbf,  // (B, L, T, CIn) bf16 (+zero row)
    const int*   __restrict__ nbr,           // (L, K)
    const unsigned short* __restrict__ wt,   // [32][288] bf16
    const float* __restrict__ bias,          // (COn,)
    float*       __restrict__ out)           // (B, L, TOn, COn)
{
    const int lane = threadIdx.x;
    const int l    = blockIdx.x;
    const int b0   = blockIdx.y * XB;     // 2 batches per block

    // one nbr line load, redistributed by shfl
    int nv = 0;
    if (lane < Kn) nv = nbr[l * Kn + lane];

    const int quad = lane >> 4;
    const int lrow = lane & 15;

    // per-lane wave-varying A offsets: voff[c] = l2[k(c,quad)]*640 + tau*16
    unsigned voff[9]; bool vld[9];
    #pragma unroll
    for (int c = 0; c < 9; ++c) {
        const int p   = c * 4 + quad;       // (k,tau) pair index, p==35 is K-pad
        const int kk  = p / 5;
        const int tau = p - kk * 5;
        const int l2  = __shfl(nv, (p >= 35) ? 0 : kk);
        vld[c]  = (p < 35) && (l2 >= 0);
        voff[c] = (unsigned)l2 * 640u + (unsigned)tau * 16u;
    }

    // ---- B fragments for BOTH o-halves (18 x bf16x8 = 72 VGPR), from global ----
    bf16x8 bfrag[2][9];
    #pragma unroll
    for (int oh = 0; oh < 2; ++oh)
        #pragma unroll
        for (int c = 0; c < 9; ++c)
            bfrag[oh][c] = *(const bf16x8*)(wt + (oh * 16 + lrow) * KPAD + c * 32 + quad * 8);
    const float bv0 = bias[lrow];
    const float bv1 = bias[16 + lrow];

    const char* xb = (const char*)xbf;

    // ---- compute: 4.5 row-tiles of 16 x 32 cols, A direct from L2 ----
    do_tiles7<0, 3, false>(xb, voff, vld, bfrag, bv0, bv1, out, b0, l, quad, lrow);
    do_tiles7<3, 2, true >(xb, voff, vld, bfrag, bv0, bv1, out, b0, l, quad, lrow);
}

// ---- fallback (original kernel) if workspace is too small ----
__global__ __launch_bounds__(256) void conv_mfma(
    const float* __restrict__ x, const int* __restrict__ nbr,
    const float* __restrict__ w, const float* __restrict__ bias,
    float* __restrict__ out)
{
    __shared__ unsigned short xs[XS_ELEMS + 8];
    __shared__ unsigned short wt[COn * WROW];

    const int tid = threadIdx.x;
    const int l   = blockIdx.x;
    const int bg  = blockIdx.y;

    for (int p = tid; p < KRED * COn; p += 256) {
        int o  = p & 31;
        int kr = p >> 5;
        wt[o * WROW + kr] = f2bf(w[p]);
    }
    for (int p = tid; p < COn * (WROW - KRED); p += 256) {
        int o = p >> 4;
        wt[o * WROW + KRED + (p & 15)] = 0;
    }
    if (tid < 8) xs[XS_ELEMS + tid] = 0;

    for (int p = tid; p < BG * Kn * 80; p += 256) {
        int b_local = p / 560;
        int r = p - b_local * 560;
        int k = r / 80;
        int q = r - k * 80;
        int l2 = nbr[l * Kn + k];
        float4 v = make_float4(0.f, 0.f, 0.f, 0.f);
        if (l2 >= 0)
            v = ((const float4*)x)[((size_t)(bg * BG + b_local) * Ln + l2) * 80 + q];
        ushort4 pk;
        pk.x = f2bf(v.x); pk.y = f2bf(v.y); pk.z = f2bf(v.z); pk.w = f2bf(v.w);
        *(ushort4*)&xs[p * 4] = pk;
    }
    __syncthreads();

    const int wave = tid >> 6;
    const int lane = tid & 63;
    const int quad = lane >> 4;
    const int lrow = lane & 15;
    const int o_base  = (wave & 1) * 16;
    const int rt_base = (wave >> 1) * 9;

    bf16x8 bfrag[9];
    #pragma unroll
    for (int c = 0; c < 9; ++c)
        bfrag[c] = *(const bf16x8*)&wt[(o_base + lrow) * WROW + c * 32 + quad * 8];

    const float bv = bias[o_base + lrow];

    #pragma unroll
    for (int g = 0; g < 3; ++g) {
        const int rt0 = rt_base + g * 3;
        f32x4 acc0 = {0.f,0.f,0.f,0.f}, acc1 = acc0, acc2 = acc0;
        const int m0 = (rt0 + 0) * 16 + lrow;
        const int m1 = (rt0 + 1) * 16 + lrow;
        const int m2 = (rt0 + 2) * 16 + lrow;
        const int bl0 = m0 / 36, t0 = m0 - bl0 * 36;
        const int bl1 = m1 / 36, t1 = m1 - bl1 * 36;
        const int bl2 = m2 / 36, t2 = m2 - bl2 * 36;
        const int base0 = bl0 * 2240 + t0 * 8;
        const int base1 = bl1 * 2240 + t1 * 8;
        const int base2 = bl2 * 2240 + t2 * 8;
        #pragma unroll
        for (int c = 0; c < 9; ++c) {
            const int p = c * 4 + quad;
            const int knbr = p / 5, tau = p - knbr * 5;
            const int koff = knbr * 320 + tau * 8;
            int o0 = base0 + koff, o1 = base1 + koff, o2 = base2 + koff;
            if (c == 8 && quad == 3) { o0 = XS_ELEMS; o1 = XS_ELEMS; o2 = XS_ELEMS; }
            bf16x8 a0 = *(const bf16x8*)&xs[o0];
            bf16x8 a1 = *(const bf16x8*)&xs[o1];
            bf16x8 a2 = *(const bf16x8*)&xs[o2];
            acc0 = __builtin_amdgcn_mfma_f32_16x16x32_bf16(a0, bfrag[c], acc0, 0, 0, 0);
            acc1 = __builtin_amdgcn_mfma_f32_16x16x32_bf16(a1, bfrag[c], acc1, 0, 0, 0);
            acc2 = __builtin_amdgcn_mfma_f32_16x16x32_bf16(a2, bfrag[c], acc2, 0, 0, 0);
        }
        #pragma unroll
        for (int i = 0; i < 3; ++i) {
            const f32x4 acc = (i == 0) ? acc0 : ((i == 1) ? acc1 : acc2);
            const int rt = rt0 + i;
            #pragma unroll
            for (int reg = 0; reg < 4; ++reg) {
                const int m  = rt * 16 + quad * 4 + reg;
                const int bl = m / 36, t = m - bl * 36;
                const size_t off =
                    (((size_t)(bg * BG + bl) * Ln + l) * TOn + t) * COn + o_base + lrow;
                out[off] = acc[reg] + bv;
            }
        }
    }
}

extern "C" void kernel_launch(void* const* d_in, const int* in_sizes, int n_in,
                              void* d_out, int out_size, void* d_ws, size_t ws_size,
                              hipStream_t stream) {
    const float* x    = (const float*)d_in[0];
    const int*   nbr  = (const int*)d_in[1];
    const float* w    = (const float*)d_in[2];
    const float* bias = (const float*)d_in[3];
    float*       out  = (float*)d_out;

    if (ws_size >= WS_NEED && d_ws != nullptr) {
        unsigned short* wt   = (unsigned short*)((char*)d_ws + WS_WT);
        unsigned short* xbf  = (unsigned short*)((char*)d_ws + WS_XBF);
        unsigned short* zrow = (unsigned short*)((char*)d_ws + WS_ZROW);
        prep_all<<<2049, 256, 0, stream>>>(x, xbf, w, wt, zrow);
        // 1 wave per block, 2 batches each: y = 16 b-pairs
        conv_mfma7<<<dim3(Ln, Bn / XB), dim3(64), 0, stream>>>(xbf, nbr, wt, bias, out);
    } else {
        conv_mfma<<<dim3(Ln, Bn / BG), dim3(256), 0, stream>>>(x, nbr, w, bias, out);
    }
}